// Round 2
// baseline (899.115 us; speedup 1.0000x reference)
//
#include <hip/hip_runtime.h>
#include <hip/hip_bf16.h>
#include <math.h>

typedef __attribute__((ext_vector_type(8))) short s8v;     // 8 bf16
typedef __attribute__((ext_vector_type(4))) float f32x4;   // MFMA C/D

#define BM 128
#define BN 128
#define BK 32
#define BKP 40  // padded LDS row stride (ushort)

__device__ __forceinline__ ushort f2bf(float x) {
    __hip_bfloat16 h = __float2bfloat16(x);
    return *(ushort*)&h;
}
__device__ __forceinline__ float bf2f(ushort u) {
    return __bfloat162float(*(__hip_bfloat16*)&u);
}

// K-index remapping (flattened element offset to ADD for TA=false, row index for TA=true)
// MAP 0: identity
// MAP 1: k & 4095          (wrap: logical K=8192 over physical 4096 rows; hi/lo lives on B side)
// MAP 2: A-side split for S-gemm on Bcat view: k<512 -> fh col (k&255); k>=512 -> fl, which
//        lives 4096 rows below in Bcat => add 4096*512 flattened elements. (TA=false only!)
// MAP 3: B-side split for W: [Wh | Wl | Wh | Wl] over k'=0..1023 on a [256][512] array
template<int MAP> __device__ __forceinline__ size_t kmap(int k) {
    if constexpr (MAP == 0) return (size_t)k;
    else if constexpr (MAP == 1) return (size_t)(k & 4095);
    else if constexpr (MAP == 2) return (k < 512) ? (size_t)(k & 255)
                                                  : ((size_t)4096 * 512 + (size_t)(k & 255));
    else return (size_t)((((k >> 8) & 1) << 8) + (k & 255));
}

// ---- load 16 contiguous elements -> bf16, contiguous LDS store ----
__device__ __forceinline__ void ld16(const ushort* src, ushort* dst) {
    *(s8v*)dst       = *(const s8v*)src;
    *(s8v*)(dst + 8) = *(const s8v*)(src + 8);
}
__device__ __forceinline__ void ld16(const float* src, ushort* dst) {
    #pragma unroll
    for (int i = 0; i < 4; i++) {
        float4 v = ((const float4*)src)[i];
        dst[4*i+0] = f2bf(v.x); dst[4*i+1] = f2bf(v.y);
        dst[4*i+2] = f2bf(v.z); dst[4*i+3] = f2bf(v.w);
    }
}
// ---- load 16 contiguous elements (along M/N), scatter into LDS column kk ----
__device__ __forceinline__ void ld16s(const ushort* src, ushort (*Ls)[BKP], int i0, int kk) {
    s8v v0 = *(const s8v*)src, v1 = *(const s8v*)(src + 8);
    #pragma unroll
    for (int u = 0; u < 8; u++) Ls[i0 + u][kk]     = ((const ushort*)&v0)[u];
    #pragma unroll
    for (int u = 0; u < 8; u++) Ls[i0 + 8 + u][kk] = ((const ushort*)&v1)[u];
}
__device__ __forceinline__ void ld16s(const float* src, ushort (*Ls)[BKP], int i0, int kk) {
    #pragma unroll
    for (int i = 0; i < 4; i++) {
        float4 v = ((const float4*)src)[i];
        Ls[i0 + 4*i + 0][kk] = f2bf(v.x); Ls[i0 + 4*i + 1][kk] = f2bf(v.y);
        Ls[i0 + 4*i + 2][kk] = f2bf(v.z); Ls[i0 + 4*i + 3][kk] = f2bf(v.w);
    }
}

// EPI: 0 = store f32 to Cp
//      1 = store bf16 to Cp
//      2 = node blend: f32 Cp = aL*blend + (1-aL)*acc
//      3 = dual: f32 to Cp AND bf16 to Cp2
//      4 = split: bf16 hi to Cp; if Cp2, bf16 lo (residual) to Cp2
template<typename AT, bool TA, int AMAP, typename BT, bool TB, int BMAP, int EPI>
__global__ __launch_bounds__(256)
void gemm_kernel(const AT* __restrict__ A, int lda, long long sA,
                 const BT* __restrict__ Bmat, int ldb, long long sB,
                 void* __restrict__ Cp, void* __restrict__ Cp2,
                 int ldc, long long sC,
                 int M, int N, int K,
                 const float* __restrict__ blend,
                 const float* __restrict__ alpha_p, const int* __restrict__ L_p)
{
    __shared__ ushort As[BM][BKP];
    __shared__ ushort Bs[BN][BKP];

    const int b  = blockIdx.z;
    const int m0 = blockIdx.x * BM;
    const int n0 = blockIdx.y * BN;
    A    += (size_t)b * sA;
    Bmat += (size_t)b * sB;

    const int t    = threadIdx.x;
    const int lane = t & 63;
    const int wid  = t >> 6;
    const int wr   = (wid >> 1) * 64;
    const int wc   = (wid & 1) * 64;
    const int lrow = lane & 15;
    const int koff = (lane >> 4) << 3;

    f32x4 acc[4][4];
    #pragma unroll
    for (int i = 0; i < 4; i++)
        #pragma unroll
        for (int j = 0; j < 4; j++) acc[i][j] = (f32x4)(0.f);

    for (int k0 = 0; k0 < K; k0 += BK) {
        // ---- stage A tile -> As[BM][BK] (bf16, K contiguous) ----
        if (!TA) {
            int row = t >> 1;
            int col = (t & 1) << 4;
            const AT* src = A + (size_t)(m0 + row) * lda + kmap<AMAP>(k0 + col);
            ld16(src, &As[row][col]);
        } else {
            int kk = t >> 3;
            int i0 = (t & 7) << 4;
            const AT* src = A + kmap<AMAP>(k0 + kk) * (size_t)lda + m0 + i0;
            ld16s(src, As, i0, kk);
        }
        // ---- stage B tile -> Bs[BN][BK] (B^T layout, K contiguous) ----
        if (!TB) {
            int row = t >> 1;
            int col = (t & 1) << 4;
            const BT* src = Bmat + (size_t)(n0 + row) * ldb + kmap<BMAP>(k0 + col);
            ld16(src, &Bs[row][col]);
        } else {
            int kk = t >> 3;
            int j0 = (t & 7) << 4;
            const BT* src = Bmat + kmap<BMAP>(k0 + kk) * (size_t)ldb + n0 + j0;
            ld16s(src, Bs, j0, kk);
        }
        __syncthreads();

        s8v af[4], bfr[4];
        #pragma unroll
        for (int mi = 0; mi < 4; mi++) af[mi]  = *(const s8v*)&As[wr + mi * 16 + lrow][koff];
        #pragma unroll
        for (int ni = 0; ni < 4; ni++) bfr[ni] = *(const s8v*)&Bs[wc + ni * 16 + lrow][koff];
        #pragma unroll
        for (int mi = 0; mi < 4; mi++)
            #pragma unroll
            for (int ni = 0; ni < 4; ni++)
                acc[mi][ni] = __builtin_amdgcn_mfma_f32_16x16x32_bf16(af[mi], bfr[ni], acc[mi][ni], 0, 0, 0);
        __syncthreads();
    }

    float aL = 0.f;
    if (EPI == 2) {
        float a = *alpha_p;
        int   L = *L_p;
        aL = powf(a, (float)L);
    }
    const int cr = (lane >> 4) << 2;
    const int cc = lane & 15;
    #pragma unroll
    for (int mi = 0; mi < 4; mi++)
        #pragma unroll
        for (int ni = 0; ni < 4; ni++)
            #pragma unroll
            for (int r = 0; r < 4; r++) {
                int row = m0 + wr + mi * 16 + cr + r;
                int col = n0 + wc + ni * 16 + cc;
                size_t idx = (size_t)b * sC + (size_t)row * ldc + col;
                float v = acc[mi][ni][r];
                if constexpr (EPI == 0) {
                    ((float*)Cp)[idx] = v;
                } else if constexpr (EPI == 1) {
                    ((ushort*)Cp)[idx] = f2bf(v);
                } else if constexpr (EPI == 2) {
                    ((float*)Cp)[idx] = aL * blend[idx] + (1.f - aL) * v;
                } else if constexpr (EPI == 3) {
                    ((float*)Cp)[idx]  = v;
                    ((ushort*)Cp2)[idx] = f2bf(v);
                } else {
                    ushort h = f2bf(v);
                    ((ushort*)Cp)[idx] = h;
                    if (Cp2) ((ushort*)Cp2)[idx] = f2bf(v - bf2f(h));
                }
            }
}

// P = softmax_e(ES) * AGG over ESAGG [b][e][512] (ES cols 0..255, AGG cols 256..511)
__global__ __launch_bounds__(256)
void softmax_mul_kernel(const float* __restrict__ ESAGG, ushort* __restrict__ P, int E)
{
    int b  = blockIdx.x >> 4;
    int d0 = (blockIdx.x & 15) << 4;
    int tx = threadIdx.x & 15;
    int ty = threadIdx.x >> 4;
    const float* es = ESAGG + (size_t)b * E * 512 + d0 + tx;
    const float* ag = es + 256;

    __shared__ float red[16][17];

    float mx = -3.4e38f;
    for (int e = ty; e < E; e += 16) mx = fmaxf(mx, es[(size_t)e * 512]);
    red[ty][tx] = mx;
    __syncthreads();
    if (ty == 0) {
        float m2 = red[0][tx];
        #pragma unroll
        for (int i = 1; i < 16; i++) m2 = fmaxf(m2, red[i][tx]);
        red[0][tx] = m2;
    }
    __syncthreads();
    mx = red[0][tx];
    __syncthreads();

    float s = 0.f;
    for (int e = ty; e < E; e += 16) s += __expf(es[(size_t)e * 512] - mx);
    red[ty][tx] = s;
    __syncthreads();
    if (ty == 0) {
        float s2 = 0.f;
        #pragma unroll
        for (int i = 0; i < 16; i++) s2 += red[i][tx];
        red[0][tx] = s2;
    }
    __syncthreads();
    float inv = 1.f / red[0][tx];

    ushort* p = P + (size_t)b * E * 256 + d0 + tx;
    for (int e = ty; e < E; e += 16) {
        float v = __expf(es[(size_t)e * 512] - mx) * inv * ag[(size_t)e * 512];
        p[(size_t)e * 256] = f2bf(v);
    }
}

// feat f32 [b][4096][256] -> Bcat cols 256..511: hi at row m, lo at row 4096+m
__global__ __launch_bounds__(256)
void cvt_feat_kernel(const float4* __restrict__ feat, ushort* __restrict__ Bcat,
                     int writeLo, int rowsB)
{
    size_t i  = (size_t)blockIdx.x * 256 + threadIdx.x;   // exactly 1048576 threads
    size_t e0 = i * 4;
    int    d  = (int)(e0 & 255);
    size_t m  = (e0 >> 8) & 4095;
    size_t bb = e0 >> 20;
    float4 v  = feat[i];
    float  a[4] = {v.x, v.y, v.z, v.w};
    ushort* hi = Bcat + bb * (size_t)rowsB * 512 + m * 512 + 256 + d;
    ushort* lo = hi + (size_t)4096 * 512;
    #pragma unroll
    for (int j = 0; j < 4; j++) {
        ushort h = f2bf(a[j]);
        hi[j] = h;
        if (writeLo) lo[j] = f2bf(a[j] - bf2f(h));
    }
}

// W f32 [256][256] -> Ws [256][512] = [Wh | Wl]
__global__ __launch_bounds__(256)
void cvt_w_kernel(const float4* __restrict__ W, ushort* __restrict__ Ws)
{
    size_t i  = (size_t)blockIdx.x * 256 + threadIdx.x;   // 16384 threads
    size_t e0 = i * 4;
    int c = (int)(e0 & 255);
    int r = (int)(e0 >> 8);
    float4 v = W[i];
    float  a[4] = {v.x, v.y, v.z, v.w};
    ushort* hi = Ws + (size_t)r * 512 + c;
    #pragma unroll
    for (int j = 0; j < 4; j++) {
        ushort h = f2bf(a[j]);
        hi[j] = h;
        hi[256 + j] = f2bf(a[j] - bf2f(h));
    }
}

// inc f32 -> f32 copy (output 2) and optional bf16 version
__global__ __launch_bounds__(256)
void inc_process_kernel(const float4* __restrict__ src, float4* __restrict__ dst,
                        ushort* __restrict__ dstBf, int writeBf, size_t n4)
{
    size_t i = (size_t)blockIdx.x * 256 + threadIdx.x;
    size_t stride = (size_t)gridDim.x * 256;
    for (; i < n4; i += stride) {
        float4 v = src[i];
        dst[i] = v;
        if (writeBf) {
            ushort4 o;
            o.x = f2bf(v.x); o.y = f2bf(v.y); o.z = f2bf(v.z); o.w = f2bf(v.w);
            ((ushort4*)dstBf)[i] = o;
        }
    }
}

extern "C" void kernel_launch(void* const* d_in, const int* in_sizes, int n_in,
                              void* d_out, int out_size, void* d_ws, size_t ws_size,
                              hipStream_t stream) {
    const float* feat    = (const float*)d_in[0];   // [4,4096,256]
    const float* inc     = (const float*)d_in[1];   // [4,4096,2048]
    const float* vcWatt  = (const float*)d_in[2];   // [256,256]
    const float* vcWproj = (const float*)d_in[3];
    // d_in[4] vc_alpha: provably unused (edge_feats == ef_base every layer)
    // d_in[5] ec_W_att: dead code in reference forward
    const float* ecWproj = (const float*)d_in[6];
    const float* ecAlpha = (const float*)d_in[7];
    const int*   nLayers = (const int*)d_in[8];

    const int Bb = 4, Mm = 4096, E = 2048, D = 256;
    const size_t nodeN = (size_t)Bb * Mm * D;
    const size_t edgeN = (size_t)Bb * E * D;
    const size_t incN  = (size_t)Bb * Mm * E;

    // ---- workspace plan (runtime-constant; graph-safe) ----
    const size_t BcatSplitB = (size_t)Bb * 8192 * 512 * 2;   // 33.55 MB
    const size_t BcatBasicB = (size_t)Bb * 4096 * 512 * 2;   // 16.78 MB
    const size_t ESAGGB = (size_t)Bb * E * 512 * 4;          // 16.78 MB
    const size_t PB     = edgeN * 2;
    const size_t EBFB   = edgeN * 2;
    const size_t WtB    = nodeN * 2;
    const size_t WsB    = (size_t)3 * 256 * 512 * 2;
    const size_t tailB  = ESAGGB + PB + EBFB + WtB + WsB;
    const size_t incbfB = incN * 2;

    const bool use_split = ws_size >= BcatSplitB + tailB;
    const bool use_incbf = ws_size >= BcatSplitB + tailB + incbfB;
    const int  rowsB = use_split ? 8192 : 4096;
    const size_t BcatB = use_split ? BcatSplitB : BcatBasicB;

    char* ws = (char*)d_ws;
    ushort* Bcat  = (ushort*)ws;
    float*  ESAGG = (float*)(ws + BcatB);
    ushort* P     = (ushort*)(ws + BcatB + ESAGGB);
    ushort* edgebf= (ushort*)(ws + BcatB + ESAGGB + PB);
    ushort* Wt    = (ushort*)(ws + BcatB + ESAGGB + PB + EBFB);
    ushort* Ws0   = (ushort*)(ws + BcatB + ESAGGB + PB + EBFB + WtB);            // vc_W_att split
    ushort* Ws1   = Ws0 + 256 * 512;                                             // vc_W_proj split
    ushort* Ws2   = Ws1 + 256 * 512;                                             // ec_W_proj split
    ushort* incbf = (ushort*)(ws + BcatB + tailB);

    float* outNode = (float*)d_out;
    float* outEdge = outNode + nodeN;
    float* outInc  = outEdge + edgeN;

    dim3 blk(256);
    const long long sBcat = (long long)rowsB * 512;

    // 0a. weight splits
    cvt_w_kernel<<<dim3(64), blk, 0, stream>>>((const float4*)vcWatt,  Ws0);
    cvt_w_kernel<<<dim3(64), blk, 0, stream>>>((const float4*)vcWproj, Ws1);
    cvt_w_kernel<<<dim3(64), blk, 0, stream>>>((const float4*)ecWproj, Ws2);
    // 0b. feat -> Bcat cols 256..511 (hi / lo)
    cvt_feat_kernel<<<dim3(4096), blk, 0, stream>>>((const float4*)feat, Bcat,
                                                    use_split ? 1 : 0, rowsB);
    // 0c. inc copy (+ optional bf16)
    inc_process_kernel<<<dim3(2048), blk, 0, stream>>>((const float4*)inc, (float4*)outInc,
                                                       incbf, use_incbf ? 1 : 0, incN / 4);

    // 1. S (f32-accurate via 4-term split) -> Bcat cols 0..255 (hi / lo)
    //    A view = Bcat+256 (feat hi/lo), B = Ws0 = [Wh|Wl], K' = 1024 (split) / 512 (basic)
    gemm_kernel<ushort,false,2, ushort,false,3, 4><<<dim3(Mm/BM, D/BN, Bb), blk, 0, stream>>>(
        Bcat + 256, 512, sBcat, Ws0, 512, 0,
        Bcat, use_split ? (void*)(Bcat + (size_t)4096 * 512) : nullptr,
        512, sBcat, Mm, D, use_split ? 1024 : 512, nullptr, nullptr, nullptr);

    // 2+3. ESAGG = inc^T @ Bcat  [b,e,512] f32   (K' = 8192 wraps inc at 4096)
    if (use_incbf) {
        gemm_kernel<ushort,true,1, ushort,true,0, 0><<<dim3(E/BM, 512/BN, Bb), blk, 0, stream>>>(
            incbf, E, (long long)Mm * E, Bcat, 512, sBcat,
            ESAGG, nullptr, 512, (long long)E * 512,
            E, 512, use_split ? 8192 : 4096, nullptr, nullptr, nullptr);
    } else {
        gemm_kernel<float,true,1, ushort,true,0, 0><<<dim3(E/BM, 512/BN, Bb), blk, 0, stream>>>(
            inc, E, (long long)Mm * E, Bcat, 512, sBcat,
            ESAGG, nullptr, 512, (long long)E * 512,
            E, 512, use_split ? 8192 : 4096, nullptr, nullptr, nullptr);
    }

    // 4. P = softmax_e(ES) * AGG  -> bf16
    softmax_mul_kernel<<<dim3(Bb * 16), blk, 0, stream>>>(ESAGG, P, E);

    // 5. edge_out = P @ vcWproj^T  -> f32 out + bf16 ws
    gemm_kernel<ushort,false,0, ushort,false,0, 3><<<dim3(E/BM, D/BN, Bb), blk, 0, stream>>>(
        P, D, (long long)E * D, Ws1, 512, 0,
        outEdge, edgebf, D, (long long)E * D,
        E, D, D, nullptr, nullptr, nullptr);

    // 6. Wt = inc @ edge_out  -> bf16
    if (use_incbf) {
        gemm_kernel<ushort,false,0, ushort,true,0, 1><<<dim3(Mm/BM, D/BN, Bb), blk, 0, stream>>>(
            incbf, E, (long long)Mm * E, edgebf, D, (long long)E * D,
            Wt, nullptr, D, (long long)Mm * D,
            Mm, D, E, nullptr, nullptr, nullptr);
    } else {
        gemm_kernel<float,false,0, ushort,true,0, 1><<<dim3(Mm/BM, D/BN, Bb), blk, 0, stream>>>(
            inc, E, (long long)Mm * E, edgebf, D, (long long)E * D,
            Wt, nullptr, D, (long long)Mm * D,
            Mm, D, E, nullptr, nullptr, nullptr);
    }

    // 7. node_out = a^L*feat + (1-a^L)*(Wt @ ecWproj^T)  -> f32 out
    gemm_kernel<ushort,false,0, ushort,false,0, 2><<<dim3(Mm/BM, D/BN, Bb), blk, 0, stream>>>(
        Wt, D, (long long)Mm * D, Ws2, 512, 0,
        outNode, nullptr, D, (long long)Mm * D,
        Mm, D, D, feat, ecAlpha, nLayers);
}

// Round 4
// 607.899 us; speedup vs baseline: 1.4791x; 1.4791x over previous
//
#include <hip/hip_runtime.h>
#include <hip/hip_bf16.h>
#include <math.h>

typedef __attribute__((ext_vector_type(8))) short s8v;     // 8 bf16
typedef __attribute__((ext_vector_type(4))) float f32x4;   // MFMA C/D

__device__ __forceinline__ ushort f2bf(float x){ __hip_bfloat16 h = __float2bfloat16(x); return *(ushort*)&h; }
__device__ __forceinline__ float  bf2f(ushort u){ return __bfloat162float(*(__hip_bfloat16*)&u); }

// K-index maps (applied to aligned 8/16-element run bases; all preserve 16-contiguity)
// 0: identity   1: k&4095 (wrap for hi/lo K=8192)   3: [Wh Wl Wh Wl]   4: [X X]   5: [fh fh fl fl]
template<int MAP> __device__ __forceinline__ int kmap(int k){
  if constexpr (MAP==0) return k;
  else if constexpr (MAP==1) return k & 4095;
  else if constexpr (MAP==3) return (((k>>8)&1)<<8) | (k&255);
  else if constexpr (MAP==4) return k & 255;
  else return (((k>>9)&1)<<8) | (k&255);
}

// ===================== GEMM =====================
// All operands bf16, natural layout: A[M][K], B[N][K] (both K-contiguous rows).
// FR=4: block 128x128 (wave 64x64). FR=2: block 64x64 (wave 32x32).
// EPI: 1 = bf16 store; 2 = blend f32 out = aL*blend+(1-aL)*v; 3 = f32 + bf16 dual;
//      4 = split hi/lo bf16 (Cp, Cp2); 5 = f32 [e][512] + transposed-f32 (cols<256) float4 to Cp2
template<int AMAP, int BMAP, int EPI, int FR>
__global__ __launch_bounds__(256)
void gemm_kernel(const ushort* __restrict__ A, int lda, long long sA,
                 const ushort* __restrict__ B, int ldb, long long sB,
                 void* __restrict__ Cp, void* __restrict__ Cp2,
                 int ldc, long long sC, long long sC2,
                 long long kpC, long long kpC2,
                 int Kloc, int kparts,
                 const float* __restrict__ blend,
                 const float* __restrict__ alpha_p, const int* __restrict__ L_p)
{
  constexpr int BMt = 32*FR;
  __shared__ ushort As[BMt][40];
  __shared__ ushort Bs[BMt][40];

  const int z  = blockIdx.z;
  const int b  = z / kparts;
  const int kp = z - b*kparts;
  const int kbase = kp * Kloc;
  A += (size_t)b * sA;
  B += (size_t)b * sB;
  const int m0 = blockIdx.x * BMt;
  const int n0 = blockIdx.y * BMt;
  const int t = threadIdx.x, lane = t & 63, wid = t >> 6;
  const int wr = (wid>>1)*(16*FR), wc = (wid&1)*(16*FR);
  const int lrow = lane & 15, koff = (lane>>4)<<3;

  f32x4 acc[FR][FR];
  #pragma unroll
  for (int i=0;i<FR;i++)
    #pragma unroll
    for (int j=0;j<FR;j++) acc[i][j] = (f32x4)(0.f);

  for (int k0 = 0; k0 < Kloc; k0 += 32) {
    if constexpr (FR==4) {
      const int row = t>>1, cb = (t&1)*16;
      { const ushort* s = A + (size_t)(m0+row)*lda + kmap<AMAP>(kbase+k0+cb);
        *(s8v*)&As[row][cb] = *(const s8v*)s; *(s8v*)&As[row][cb+8] = *(const s8v*)(s+8); }
      { const ushort* s = B + (size_t)(n0+row)*ldb + kmap<BMAP>(kbase+k0+cb);
        *(s8v*)&Bs[row][cb] = *(const s8v*)s; *(s8v*)&Bs[row][cb+8] = *(const s8v*)(s+8); }
    } else {
      const int row = t>>2, cb = (t&3)*8;
      *(s8v*)&As[row][cb] = *(const s8v*)(A + (size_t)(m0+row)*lda + kmap<AMAP>(kbase+k0+cb));
      *(s8v*)&Bs[row][cb] = *(const s8v*)(B + (size_t)(n0+row)*ldb + kmap<BMAP>(kbase+k0+cb));
    }
    __syncthreads();
    s8v af[FR], bfv[FR];
    #pragma unroll
    for (int mi=0; mi<FR; mi++) af[mi]  = *(const s8v*)&As[wr+mi*16+lrow][koff];
    #pragma unroll
    for (int ni=0; ni<FR; ni++) bfv[ni] = *(const s8v*)&Bs[wc+ni*16+lrow][koff];
    #pragma unroll
    for (int mi=0; mi<FR; mi++)
      #pragma unroll
      for (int ni=0; ni<FR; ni++)
        acc[mi][ni] = __builtin_amdgcn_mfma_f32_16x16x32_bf16(af[mi], bfv[ni], acc[mi][ni], 0,0,0);
    __syncthreads();
  }

  float aL = 0.f;
  if constexpr (EPI==2) { aL = powf(*alpha_p, (float)(*L_p)); }
  const int cr = (lane>>4)<<2, cc = lane & 15;
  #pragma unroll
  for (int mi=0; mi<FR; mi++)
    #pragma unroll
    for (int ni=0; ni<FR; ni++) {
      const int row0 = m0 + wr + mi*16 + cr;
      const int col  = n0 + wc + ni*16 + cc;
      if constexpr (EPI==5) {
        float* C = (float*)Cp + kp*kpC + (size_t)b*sC;
        #pragma unroll
        for (int r=0;r<4;r++) C[(size_t)(row0+r)*ldc + col] = acc[mi][ni][r];
        if (col < 256) {
          float* C2 = (float*)Cp2 + kp*kpC2 + (size_t)b*sC2 + (size_t)col*2048 + row0;
          *(f32x4*)C2 = acc[mi][ni];
        }
      } else {
        #pragma unroll
        for (int r=0;r<4;r++) {
          const size_t idx = (size_t)b*sC + (size_t)(row0+r)*ldc + col;
          const float v = acc[mi][ni][r];
          if constexpr (EPI==1) ((ushort*)Cp)[idx] = f2bf(v);
          else if constexpr (EPI==2) ((float*)Cp)[idx] = aL*blend[idx] + (1.f-aL)*v;
          else if constexpr (EPI==3) { ((float*)Cp)[idx] = v; ((ushort*)Cp2)[idx] = f2bf(v); }
          else { ushort h = f2bf(v); ((ushort*)Cp)[idx] = h; ((ushort*)Cp2)[idx] = f2bf(v - bf2f(h)); }
        }
      }
    }
}

// ===================== transposes =====================
// inc f32 [b][4096][2048] -> incbf bf16 straight + incT bf16 [b][2048][4096]
__global__ __launch_bounds__(256)
void trans_inc_kernel(const float* __restrict__ src, ushort* __restrict__ incbf,
                      ushort* __restrict__ incT)
{
  __shared__ ushort T[64][65];
  const int b = blockIdx.z, m0 = blockIdx.x*64, e0 = blockIdx.y*64;
  const int t = threadIdx.x, rl = t>>2, cl = (t&3)*16;
  const float* s = src + (size_t)b*4096*2048 + (size_t)(m0+rl)*2048 + e0 + cl;
  ushort tmp[16] __attribute__((aligned(16)));
  #pragma unroll
  for (int i=0;i<4;i++) {
    float4 v = ((const float4*)s)[i];
    tmp[4*i+0]=f2bf(v.x); tmp[4*i+1]=f2bf(v.y); tmp[4*i+2]=f2bf(v.z); tmp[4*i+3]=f2bf(v.w);
  }
  ushort* d = incbf + (size_t)b*4096*2048 + (size_t)(m0+rl)*2048 + e0 + cl;
  *(s8v*)d = *(s8v*)&tmp[0]; *(s8v*)(d+8) = *(s8v*)&tmp[8];
  #pragma unroll
  for (int j=0;j<16;j++) T[rl][cl+j] = tmp[j];
  __syncthreads();
  const int er = t>>2, mc = (t&3)*16;
  ushort o[16] __attribute__((aligned(16)));
  #pragma unroll
  for (int j=0;j<16;j++) o[j] = T[mc+j][er];
  ushort* d2 = incT + (size_t)b*2048*4096 + (size_t)(e0+er)*4096 + m0 + mc;
  *(s8v*)d2 = *(s8v*)&o[0]; *(s8v*)(d2+8) = *(s8v*)&o[8];
}

// feat f32 [b][4096][256] -> fcat bf16 [b][4096][512]=[fh|fl] + BcatT rows 256..511 (hi; lo at col+4096)
__global__ __launch_bounds__(256)
void trans_feat_kernel(const float* __restrict__ feat, ushort* __restrict__ fcat,
                       ushort* __restrict__ BcatT)
{
  __shared__ ushort Th[64][65], Tl[64][65];
  const int b = blockIdx.z, m0 = blockIdx.x*64, d0 = blockIdx.y*64;
  const int t = threadIdx.x, rl = t>>2, cl = (t&3)*16;
  const float* s = feat + (size_t)b*4096*256 + (size_t)(m0+rl)*256 + d0 + cl;
  ushort hi[16] __attribute__((aligned(16)));
  ushort lo[16] __attribute__((aligned(16)));
  #pragma unroll
  for (int i=0;i<4;i++) {
    float4 v = ((const float4*)s)[i];
    float a[4] = {v.x,v.y,v.z,v.w};
    #pragma unroll
    for (int j=0;j<4;j++) {
      ushort h = f2bf(a[j]); hi[4*i+j] = h; lo[4*i+j] = f2bf(a[j] - bf2f(h));
    }
  }
  ushort* d = fcat + (size_t)b*4096*512 + (size_t)(m0+rl)*512 + d0 + cl;
  *(s8v*)d = *(s8v*)&hi[0]; *(s8v*)(d+8) = *(s8v*)&hi[8];
  *(s8v*)(d+256) = *(s8v*)&lo[0]; *(s8v*)(d+264) = *(s8v*)&lo[8];
  #pragma unroll
  for (int j=0;j<16;j++) { Th[rl][cl+j] = hi[j]; Tl[rl][cl+j] = lo[j]; }
  __syncthreads();
  const int dr = t>>2, mc = (t&3)*16;
  ushort oh[16] __attribute__((aligned(16)));
  ushort ol[16] __attribute__((aligned(16)));
  #pragma unroll
  for (int j=0;j<16;j++) { oh[j] = Th[mc+j][dr]; ol[j] = Tl[mc+j][dr]; }
  ushort* d2 = BcatT + (size_t)b*512*8192 + (size_t)(256+d0+dr)*8192 + m0 + mc;
  *(s8v*)d2 = *(s8v*)&oh[0]; *(s8v*)(d2+8) = *(s8v*)&oh[8];
  *(s8v*)(d2+4096) = *(s8v*)&ol[0]; *(s8v*)(d2+4104) = *(s8v*)&ol[8];
}

// generic bf16 [b][R][C] -> dst[b][c][colOff + r]
__global__ __launch_bounds__(256)
void trans_bf_kernel(const ushort* __restrict__ src, int srcLd, long long srcB,
                     ushort* __restrict__ dst, int dstLd, long long dstB, int colOff)
{
  __shared__ ushort T[64][65];
  const int b = blockIdx.z, r0 = blockIdx.x*64, c0 = blockIdx.y*64;
  const int t = threadIdx.x, rl = t>>2, cl = (t&3)*16;
  const ushort* s = src + (size_t)b*srcB + (size_t)(r0+rl)*srcLd + c0 + cl;
  s8v v0 = *(const s8v*)s, v1 = *(const s8v*)(s+8);
  #pragma unroll
  for (int j=0;j<8;j++) { T[rl][cl+j] = ((const ushort*)&v0)[j]; T[rl][cl+8+j] = ((const ushort*)&v1)[j]; }
  __syncthreads();
  const int cr = t>>2, rc = (t&3)*16;
  ushort o[16] __attribute__((aligned(16)));
  #pragma unroll
  for (int j=0;j<16;j++) o[j] = T[rc+j][cr];
  ushort* d = dst + (size_t)b*dstB + (size_t)(c0+cr)*dstLd + colOff + r0 + rc;
  *(s8v*)d = *(s8v*)&o[0]; *(s8v*)(d+8) = *(s8v*)&o[8];
}

// W f32 [256][256] -> Ws [256][512] = [Wh | Wl]
__global__ __launch_bounds__(256)
void cvt_w_kernel(const float4* __restrict__ W, ushort* __restrict__ Ws)
{
  size_t i  = (size_t)blockIdx.x * 256 + threadIdx.x;   // 16384 threads
  size_t e0 = i * 4;
  int c = (int)(e0 & 255), r = (int)(e0 >> 8);
  float4 v = W[i];
  float a[4] = {v.x,v.y,v.z,v.w};
  ushort* hi = Ws + (size_t)r*512 + c;
  #pragma unroll
  for (int j=0;j<4;j++) { ushort h = f2bf(a[j]); hi[j] = h; hi[256+j] = f2bf(a[j]-bf2f(h)); }
}

// ===================== softmax =====================
// per (b,d): max & 1/sum of sum-of-parts ES over e (ESt layout [kp][b][256][2048])
__global__ __launch_bounds__(256)
void stats_kernel(const float* __restrict__ ESt, long long kpC2, int kparts,
                  float2* __restrict__ stats)
{
  const int b = blockIdx.x >> 8, d = blockIdx.x & 255;
  const float* base = ESt + (size_t)b*256*2048 + (size_t)d*2048;
  const int t = threadIdx.x;
  float v[8] = {0,0,0,0,0,0,0,0};
  for (int kp=0; kp<kparts; kp++) {
    const float4* p = (const float4*)(base + (size_t)kp*kpC2) + t*2;
    float4 x = p[0], y = p[1];
    v[0]+=x.x; v[1]+=x.y; v[2]+=x.z; v[3]+=x.w;
    v[4]+=y.x; v[5]+=y.y; v[6]+=y.z; v[7]+=y.w;
  }
  float mx = v[0];
  #pragma unroll
  for (int j=1;j<8;j++) mx = fmaxf(mx, v[j]);
  #pragma unroll
  for (int off=32; off>=1; off>>=1) mx = fmaxf(mx, __shfl_down(mx, off));
  __shared__ float sm[8];
  const int lane = t & 63, w = t >> 6;
  if (lane==0) sm[w] = mx;
  __syncthreads();
  if (t==0) { float m = fmaxf(fmaxf(sm[0],sm[1]),fmaxf(sm[2],sm[3])); sm[4] = m; }
  __syncthreads();
  mx = sm[4];
  float s = 0.f;
  #pragma unroll
  for (int j=0;j<8;j++) s += __expf(v[j]-mx);
  #pragma unroll
  for (int off=32; off>=1; off>>=1) s += __shfl_down(s, off);
  if (lane==0) sm[w] = s;
  __syncthreads();
  if (t==0) { float ss = sm[0]+sm[1]+sm[2]+sm[3]; stats[blockIdx.x] = make_float2(mx, 1.f/ss); }
}

// P[b][e][d] = exp(ES-mx)*inv * AGG   (ESAGG parts layout [kp][b][e][512])
__global__ __launch_bounds__(256)
void pmul_kernel(const float* __restrict__ ESAGG, long long kpC, int kparts,
                 const float2* __restrict__ stats, ushort* __restrict__ P)
{
  const int bx = blockIdx.x;
  const int b = bx >> 7, e0 = (bx & 127) * 16;
  const int t = threadIdx.x, er = t >> 4, dc = (t & 15) * 16;
  const int row = e0 + er;
  const size_t base = (size_t)b*2048*512 + (size_t)row*512 + dc;
  float es[16] = {0}, ag[16] = {0};
  for (int kp=0; kp<kparts; kp++) {
    const float4* p = (const float4*)(ESAGG + (size_t)kp*kpC + base);
    const float4* q = p + 64;  // +256 floats = AGG
    #pragma unroll
    for (int i=0;i<4;i++) {
      float4 a = p[i], c = q[i];
      es[4*i+0]+=a.x; es[4*i+1]+=a.y; es[4*i+2]+=a.z; es[4*i+3]+=a.w;
      ag[4*i+0]+=c.x; ag[4*i+1]+=c.y; ag[4*i+2]+=c.z; ag[4*i+3]+=c.w;
    }
  }
  ushort o[16] __attribute__((aligned(16)));
  #pragma unroll
  for (int j=0;j<16;j++) {
    float2 st = stats[b*256 + dc + j];
    o[j] = f2bf(__expf(es[j]-st.x) * st.y * ag[j]);
  }
  ushort* d = P + (size_t)b*2048*256 + (size_t)row*256 + dc;
  *(s8v*)d = *(s8v*)&o[0]; *(s8v*)(d+8) = *(s8v*)&o[8];
}

__global__ __launch_bounds__(256)
void inc_copy_kernel(const float4* __restrict__ src, float4* __restrict__ dst, size_t n4)
{
  size_t i = (size_t)blockIdx.x*256 + threadIdx.x;
  const size_t stride = (size_t)gridDim.x*256;
  for (; i < n4; i += stride) dst[i] = src[i];
}

// ===================== host =====================
extern "C" void kernel_launch(void* const* d_in, const int* in_sizes, int n_in,
                              void* d_out, int out_size, void* d_ws, size_t ws_size,
                              hipStream_t stream) {
  const float* feat    = (const float*)d_in[0];
  const float* inc     = (const float*)d_in[1];
  const float* vcWatt  = (const float*)d_in[2];
  const float* vcWproj = (const float*)d_in[3];
  // d_in[4] vc_alpha: unused (edge_feats == ef_base every layer); d_in[5] ec_W_att: dead code
  const float* ecWproj = (const float*)d_in[6];
  const float* ecAlpha = (const float*)d_in[7];
  const int*   nLayers = (const int*)d_in[8];

  const int Bb=4, Mm=4096, E=2048, D=256;
  const size_t nodeN = (size_t)Bb*Mm*D, edgeN = (size_t)Bb*E*D, incN = (size_t)Bb*Mm*E;

  // ws layout
  const size_t BcatTB = (size_t)Bb*512*8192*2;      // 33.55MB
  const size_t fcatB  = (size_t)Bb*4096*512*2;      // 16.78MB
  const size_t ShB    = nodeN*2, SlB = nodeN*2;     // 8.39 each
  const size_t PB     = edgeN*2, ebfB = edgeN*2, eTB = edgeN*2;
  const size_t WtB    = nodeN*2;
  const size_t WsB    = (size_t)3*256*512*2;
  const size_t statB  = (size_t)Bb*256*sizeof(float2);
  const size_t fixedB = BcatTB+fcatB+ShB+SlB+PB+ebfB+eTB+WtB+WsB+statB;
  const size_t perKp  = (size_t)Bb*E*512*4 + (size_t)Bb*256*2048*4;  // ESAGGp + ESt
  int kparts = 1;
  if (ws_size >= fixedB + 4*perKp) kparts = 4;
  else if (ws_size >= fixedB + 2*perKp) kparts = 2;

  char* ws = (char*)d_ws;
  ushort* BcatT = (ushort*)ws;                    ws += BcatTB;
  ushort* fcat  = (ushort*)ws;                    ws += fcatB;
  ushort* Sh    = (ushort*)ws;                    ws += ShB;
  ushort* Sl    = (ushort*)ws;                    ws += SlB;
  ushort* P     = (ushort*)ws;                    ws += PB;
  ushort* edgebf= (ushort*)ws;                    ws += ebfB;
  ushort* edgeT = (ushort*)ws;                    ws += eTB;
  ushort* Wt    = (ushort*)ws;                    ws += WtB;
  ushort* Ws0   = (ushort*)ws;
  ushort* Ws1   = Ws0 + 256*512;
  ushort* Ws2   = Ws1 + 256*512;                  ws += WsB;
  float2* stats = (float2*)ws;                    ws += statB;
  float*  ESAGGp= (float*)ws;                     // kparts * Bb*E*512
  float*  ESt   = ESAGGp + (size_t)kparts*Bb*E*512;

  float* outNode = (float*)d_out;
  float* outEdge = outNode + nodeN;
  float* outInc  = outEdge + edgeN;
  // incT/incbf scratch inside the outInc region (rewritten by final copy)
  ushort* incT  = (ushort*)outInc;                        // Bb*2048*4096 bf16 = 67.1MB
  ushort* incbf = incT + (size_t)Bb*2048*4096;            // Bb*4096*2048 bf16 = 67.1MB

  const long long kpC  = (long long)Bb*E*512;     // ESAGG part stride (floats)
  const long long kpC2 = (long long)Bb*256*2048;  // ESt part stride (floats)
  dim3 blk(256);

  // 0. conversions / transposes
  cvt_w_kernel<<<dim3(64), blk, 0, stream>>>((const float4*)vcWatt,  Ws0);
  cvt_w_kernel<<<dim3(64), blk, 0, stream>>>((const float4*)vcWproj, Ws1);
  cvt_w_kernel<<<dim3(64), blk, 0, stream>>>((const float4*)ecWproj, Ws2);
  trans_feat_kernel<<<dim3(64,4,4), blk, 0, stream>>>(feat, fcat, BcatT);
  trans_inc_kernel<<<dim3(64,32,4), blk, 0, stream>>>(inc, incbf, incT);

  // 1. S = (fh+fl)@(Wh+Wl)^T  -> Sh,Sl   (K'=1024)
  gemm_kernel<5,3,4,2><<<dim3(64,4,4), blk, 0, stream>>>(
      fcat, 512, (long long)Mm*512, Ws0, 512, 0,
      Sh, Sl, D, (long long)Mm*D, 0, 0, 0, 1024, 1, nullptr, nullptr, nullptr);
  trans_bf_kernel<<<dim3(64,4,4), blk, 0, stream>>>(Sh, 256, (long long)Mm*D, BcatT, 8192, (long long)512*8192, 0);
  trans_bf_kernel<<<dim3(64,4,4), blk, 0, stream>>>(Sl, 256, (long long)Mm*D, BcatT, 8192, (long long)512*8192, 4096);

  // 2. ESAGG = incT @ BcatT^T  (K=8192 logical, split into kparts) + transposed ES
  gemm_kernel<1,0,5,4><<<dim3(16,4,4*kparts), blk, 0, stream>>>(
      incT, 4096, (long long)E*4096, BcatT, 8192, (long long)512*8192,
      ESAGGp, ESt, 512, (long long)E*512, (long long)256*2048,
      kpC, kpC2, 8192/kparts, kparts, nullptr, nullptr, nullptr);

  // 3. softmax stats + P
  stats_kernel<<<dim3(Bb*256), blk, 0, stream>>>(ESt, kpC2, kparts, stats);
  pmul_kernel<<<dim3(Bb*128), blk, 0, stream>>>(ESAGGp, kpC, kparts, stats, P);

  // 4. edge_out = P @ vcWproj^T  (K'=512) -> f32 out + bf16
  gemm_kernel<4,3,3,2><<<dim3(32,4,4), blk, 0, stream>>>(
      P, 256, (long long)E*D, Ws1, 512, 0,
      outEdge, edgebf, D, (long long)E*D, 0, 0, 0, 512, 1, nullptr, nullptr, nullptr);
  trans_bf_kernel<<<dim3(32,4,4), blk, 0, stream>>>(edgebf, 256, (long long)E*D, edgeT, 2048, (long long)256*2048, 0);

  // 5. Wt = inc @ edge_out  (K=2048)
  gemm_kernel<0,0,1,2><<<dim3(64,4,4), blk, 0, stream>>>(
      incbf, 2048, (long long)Mm*E, edgeT, 2048, (long long)256*2048,
      Wt, nullptr, D, (long long)Mm*D, 0, 0, 0, 2048, 1, nullptr, nullptr, nullptr);

  // 6. node_out = a^L*feat + (1-a^L)*(Wt @ ecWproj^T)  (K'=512)
  gemm_kernel<4,3,2,2><<<dim3(64,4,4), blk, 0, stream>>>(
      Wt, 256, (long long)Mm*D, Ws2, 512, 0,
      outNode, nullptr, D, (long long)Mm*D, 0, 0, 0, 512, 1, feat, ecAlpha, nLayers);

  // 7. final inc passthrough (overwrites the incT/incbf scratch)
  inc_copy_kernel<<<dim3(2048), blk, 0, stream>>>((const float4*)inc, (float4*)outInc, incN/4);
}

// Round 5
// 527.514 us; speedup vs baseline: 1.7044x; 1.1524x over previous
//
#include <hip/hip_runtime.h>
#include <hip/hip_bf16.h>
#include <math.h>

typedef __attribute__((ext_vector_type(8))) short s8v;     // 8 bf16
typedef __attribute__((ext_vector_type(4))) float f32x4;   // MFMA C/D

__device__ __forceinline__ ushort f2bf(float x){ __hip_bfloat16 h = __float2bfloat16(x); return *(ushort*)&h; }
__device__ __forceinline__ float  bf2f(ushort u){ return __bfloat162float(*(__hip_bfloat16*)&u); }

// K-index maps (applied to aligned 8/16-element run bases; all preserve 8/16-contiguity)
// 0: identity   1: k&4095 (wrap: K=8192 over 4096 rows; hi/lo on other side)
// 3: [Wh Wl Wh Wl] on [256][512]   4: [X X] (dup 256-col)   5: [Ah Ah Al Al] on [*][512]
template<int MAP> __device__ __forceinline__ int kmap(int k){
  if constexpr (MAP==0) return k;
  else if constexpr (MAP==1) return k & 4095;
  else if constexpr (MAP==3) return (((k>>8)&1)<<8) | (k&255);
  else if constexpr (MAP==4) return k & 255;
  else return (((k>>9)&1)<<8) | (k&255);
}

// ===================== GEMM =====================
// Operands bf16, natural layout: A[M][K], B[N][K] (K contiguous).
// FR=4: 128x128 block (wave 64x64). FR=2: 64x64 block (wave 32x32).
// EPI: 0 = f32 C (+kp part offset); 1 = bf16 C; 2 = blend f32 C = aL*blend+(1-aL)*v;
//      6 = f32 C + f32 transposed C2 (float4 along rows); 7 = f32 C + bf16 transposed C2
template<int AMAP, int BMAP, int EPI, int FR>
__global__ __launch_bounds__(256)
void gemm_kernel(const ushort* __restrict__ A, int lda, long long sA,
                 const ushort* __restrict__ B, int ldb, long long sB,
                 void* __restrict__ Cp, void* __restrict__ Cp2,
                 int ldc, long long sC, int ldc2, long long sC2,
                 long long kpC, int Kloc, int kparts,
                 const float* __restrict__ blend,
                 const float* __restrict__ alpha_p, const int* __restrict__ L_p)
{
  constexpr int BMt = 32*FR;
  __shared__ ushort As[BMt][40];
  __shared__ ushort Bs[BMt][40];

  const int z  = blockIdx.z;
  const int b  = z / kparts;
  const int kp = z - b*kparts;
  const int kbase = kp * Kloc;
  A += (size_t)b * sA;
  B += (size_t)b * sB;
  const int m0 = blockIdx.x * BMt;
  const int n0 = blockIdx.y * BMt;
  const int t = threadIdx.x, lane = t & 63, wid = t >> 6;
  const int wr = (wid>>1)*(16*FR), wc = (wid&1)*(16*FR);
  const int lrow = lane & 15, koff = (lane>>4)<<3;

  f32x4 acc[FR][FR];
  #pragma unroll
  for (int i=0;i<FR;i++)
    #pragma unroll
    for (int j=0;j<FR;j++) acc[i][j] = (f32x4)(0.f);

  for (int k0 = 0; k0 < Kloc; k0 += 32) {
    if constexpr (FR==4) {
      const int row = t>>1, cb = (t&1)*16;
      { const ushort* s = A + (size_t)(m0+row)*lda + kmap<AMAP>(kbase+k0+cb);
        *(s8v*)&As[row][cb] = *(const s8v*)s; *(s8v*)&As[row][cb+8] = *(const s8v*)(s+8); }
      { const ushort* s = B + (size_t)(n0+row)*ldb + kmap<BMAP>(kbase+k0+cb);
        *(s8v*)&Bs[row][cb] = *(const s8v*)s; *(s8v*)&Bs[row][cb+8] = *(const s8v*)(s+8); }
    } else {
      const int row = t>>2, cb = (t&3)*8;
      *(s8v*)&As[row][cb] = *(const s8v*)(A + (size_t)(m0+row)*lda + kmap<AMAP>(kbase+k0+cb));
      *(s8v*)&Bs[row][cb] = *(const s8v*)(B + (size_t)(n0+row)*ldb + kmap<BMAP>(kbase+k0+cb));
    }
    __syncthreads();
    s8v af[FR], bfv[FR];
    #pragma unroll
    for (int mi=0; mi<FR; mi++) af[mi]  = *(const s8v*)&As[wr+mi*16+lrow][koff];
    #pragma unroll
    for (int ni=0; ni<FR; ni++) bfv[ni] = *(const s8v*)&Bs[wc+ni*16+lrow][koff];
    #pragma unroll
    for (int mi=0; mi<FR; mi++)
      #pragma unroll
      for (int ni=0; ni<FR; ni++)
        acc[mi][ni] = __builtin_amdgcn_mfma_f32_16x16x32_bf16(af[mi], bfv[ni], acc[mi][ni], 0,0,0);
    __syncthreads();
  }

  float aL = 0.f;
  if constexpr (EPI==2) { aL = powf(*alpha_p, (float)(*L_p)); }
  const int cr = (lane>>4)<<2, cc = lane & 15;
  #pragma unroll
  for (int mi=0; mi<FR; mi++)
    #pragma unroll
    for (int ni=0; ni<FR; ni++) {
      const int row0 = m0 + wr + mi*16 + cr;
      const int col  = n0 + wc + ni*16 + cc;
      if constexpr (EPI==0) {
        float* C = (float*)Cp + kp*kpC + (size_t)b*sC;
        #pragma unroll
        for (int r=0;r<4;r++) C[(size_t)(row0+r)*ldc + col] = acc[mi][ni][r];
      } else if constexpr (EPI==1) {
        ushort* C = (ushort*)Cp + (size_t)b*sC;
        #pragma unroll
        for (int r=0;r<4;r++) C[(size_t)(row0+r)*ldc + col] = f2bf(acc[mi][ni][r]);
      } else if constexpr (EPI==2) {
        float* C = (float*)Cp + (size_t)b*sC;
        const float* bl = blend + (size_t)b*sC;
        #pragma unroll
        for (int r=0;r<4;r++) {
          const size_t idx = (size_t)(row0+r)*ldc + col;
          C[idx] = aL*bl[idx] + (1.f-aL)*acc[mi][ni][r];
        }
      } else if constexpr (EPI==6) {
        float* C = (float*)Cp + (size_t)b*sC;
        #pragma unroll
        for (int r=0;r<4;r++) C[(size_t)(row0+r)*ldc + col] = acc[mi][ni][r];
        float* C2 = (float*)Cp2 + (size_t)b*sC2 + (size_t)col*ldc2 + row0;
        *(f32x4*)C2 = acc[mi][ni];
      } else {  // EPI==7
        float* C = (float*)Cp + (size_t)b*sC;
        #pragma unroll
        for (int r=0;r<4;r++) C[(size_t)(row0+r)*ldc + col] = acc[mi][ni][r];
        ushort4 o;
        o.x = f2bf(acc[mi][ni][0]); o.y = f2bf(acc[mi][ni][1]);
        o.z = f2bf(acc[mi][ni][2]); o.w = f2bf(acc[mi][ni][3]);
        *(ushort4*)((ushort*)Cp2 + (size_t)b*sC2 + (size_t)col*ldc2 + row0) = o;
      }
    }
}

// ===================== transposes =====================
// inc f32 [b][4096][2048] -> incbf bf16 straight + incT bf16 [b][2048][4096]
// (+ optional direct f32 passthrough to outInc in plan A)
__global__ __launch_bounds__(256)
void trans_inc_kernel(const float* __restrict__ src, float* __restrict__ outF32, int writeF32,
                      ushort* __restrict__ incbf, ushort* __restrict__ incT)
{
  __shared__ ushort T[64][65];
  const int b = blockIdx.z, m0 = blockIdx.x*64, e0 = blockIdx.y*64;
  const int t = threadIdx.x, rl = t>>2, cl = (t&3)*16;
  const size_t roff = (size_t)b*4096*2048 + (size_t)(m0+rl)*2048 + e0 + cl;
  const float* s = src + roff;
  ushort tmp[16] __attribute__((aligned(16)));
  float4 vv[4];
  #pragma unroll
  for (int i=0;i<4;i++) {
    vv[i] = ((const float4*)s)[i];
    tmp[4*i+0]=f2bf(vv[i].x); tmp[4*i+1]=f2bf(vv[i].y);
    tmp[4*i+2]=f2bf(vv[i].z); tmp[4*i+3]=f2bf(vv[i].w);
  }
  if (writeF32) {
    float4* o = (float4*)(outF32 + roff);
    #pragma unroll
    for (int i=0;i<4;i++) o[i] = vv[i];
  }
  ushort* d = incbf + roff;
  *(s8v*)d = *(s8v*)&tmp[0]; *(s8v*)(d+8) = *(s8v*)&tmp[8];
  #pragma unroll
  for (int j=0;j<16;j++) T[rl][cl+j] = tmp[j];
  __syncthreads();
  const int er = t>>2, mc = (t&3)*16;
  ushort o[16] __attribute__((aligned(16)));
  #pragma unroll
  for (int j=0;j<16;j++) o[j] = T[mc+j][er];
  ushort* d2 = incT + (size_t)b*2048*4096 + (size_t)(e0+er)*4096 + m0 + mc;
  *(s8v*)d2 = *(s8v*)&o[0]; *(s8v*)(d2+8) = *(s8v*)&o[8];
}

// feat f32 [b][4096][256] -> fT bf16 [b][256][8192]: hi at col m, lo at col 4096+m
__global__ __launch_bounds__(256)
void trans_feat_kernel(const float* __restrict__ feat, ushort* __restrict__ fT)
{
  __shared__ ushort Th[64][65], Tl[64][65];
  const int b = blockIdx.z, m0 = blockIdx.x*64, d0 = blockIdx.y*64;
  const int t = threadIdx.x, rl = t>>2, cl = (t&3)*16;
  const float* s = feat + (size_t)b*4096*256 + (size_t)(m0+rl)*256 + d0 + cl;
  #pragma unroll
  for (int i=0;i<4;i++) {
    float4 v = ((const float4*)s)[i];
    float a[4] = {v.x,v.y,v.z,v.w};
    #pragma unroll
    for (int j=0;j<4;j++) {
      ushort h = f2bf(a[j]); Th[rl][cl+4*i+j] = h; Tl[rl][cl+4*i+j] = f2bf(a[j] - bf2f(h));
    }
  }
  __syncthreads();
  const int dr = t>>2, mc = (t&3)*16;
  ushort oh[16] __attribute__((aligned(16)));
  ushort ol[16] __attribute__((aligned(16)));
  #pragma unroll
  for (int j=0;j<16;j++) { oh[j] = Th[mc+j][dr]; ol[j] = Tl[mc+j][dr]; }
  ushort* d2 = fT + (size_t)b*256*8192 + (size_t)(d0+dr)*8192 + m0 + mc;
  *(s8v*)d2 = *(s8v*)&oh[0]; *(s8v*)(d2+8) = *(s8v*)&oh[8];
  *(s8v*)(d2+4096) = *(s8v*)&ol[0]; *(s8v*)(d2+4104) = *(s8v*)&ol[8];
}

// W f32 [256][256] -> Ws [256][512] = [Wh | Wl]
__global__ __launch_bounds__(256)
void cvt_w_kernel(const float4* __restrict__ W, ushort* __restrict__ Ws)
{
  size_t i  = (size_t)blockIdx.x * 256 + threadIdx.x;
  size_t e0 = i * 4;
  int c = (int)(e0 & 255), r = (int)(e0 >> 8);
  float4 v = W[i];
  float a[4] = {v.x,v.y,v.z,v.w};
  ushort* hi = Ws + (size_t)r*512 + c;
  #pragma unroll
  for (int j=0;j<4;j++) { ushort h = f2bf(a[j]); hi[j] = h; hi[256+j] = f2bf(a[j]-bf2f(h)); }
}

// sum split-K AGG parts -> AGGcat bf16 [b*2048][512] = [Ah | Al]
__global__ __launch_bounds__(256)
void aggsum_kernel(const float* __restrict__ parts, long long kpC, int kparts,
                   ushort* __restrict__ AGGcat)
{
  const size_t i4 = (size_t)blockIdx.x*256 + threadIdx.x;  // 524288 float4s
  float4 sv = make_float4(0.f,0.f,0.f,0.f);
  for (int kp=0; kp<kparts; kp++) {
    float4 v = ((const float4*)(parts + (size_t)kp*kpC))[i4];
    sv.x+=v.x; sv.y+=v.y; sv.z+=v.z; sv.w+=v.w;
  }
  const size_t flat = i4*4;
  const size_t row = flat >> 8;
  const int d = (int)(flat & 255);
  float a[4] = {sv.x, sv.y, sv.z, sv.w};
  ushort4 hi, lo;
  { ushort h=f2bf(a[0]); hi.x=h; lo.x=f2bf(a[0]-bf2f(h)); }
  { ushort h=f2bf(a[1]); hi.y=h; lo.y=f2bf(a[1]-bf2f(h)); }
  { ushort h=f2bf(a[2]); hi.z=h; lo.z=f2bf(a[2]-bf2f(h)); }
  { ushort h=f2bf(a[3]); hi.w=h; lo.w=f2bf(a[3]-bf2f(h)); }
  ushort* dst = AGGcat + row*512 + d;
  *(ushort4*)dst = hi; *(ushort4*)(dst+256) = lo;
}

// ===================== softmax =====================
// per (b,d): max & 1/sum over e of ESt [b][256][2048] f32
__global__ __launch_bounds__(256)
void stats_kernel(const float* __restrict__ ESt, float2* __restrict__ stats)
{
  const int b = blockIdx.x >> 8, d = blockIdx.x & 255;
  const float* base = ESt + ((size_t)b*256 + d)*2048;
  const int t = threadIdx.x;
  const float4* p = (const float4*)base + t*2;
  float4 x = p[0], y = p[1];
  float v[8] = {x.x,x.y,x.z,x.w,y.x,y.y,y.z,y.w};
  float mx = v[0];
  #pragma unroll
  for (int j=1;j<8;j++) mx = fmaxf(mx, v[j]);
  #pragma unroll
  for (int off=32; off>=1; off>>=1) mx = fmaxf(mx, __shfl_down(mx, off));
  __shared__ float sm[8];
  const int lane = t & 63, w = t >> 6;
  if (lane==0) sm[w] = mx;
  __syncthreads();
  if (t==0) { sm[4] = fmaxf(fmaxf(sm[0],sm[1]),fmaxf(sm[2],sm[3])); }
  __syncthreads();
  mx = sm[4];
  float s = 0.f;
  #pragma unroll
  for (int j=0;j<8;j++) s += __expf(v[j]-mx);
  #pragma unroll
  for (int off=32; off>=1; off>>=1) s += __shfl_down(s, off);
  if (lane==0) sm[w] = s;
  __syncthreads();
  if (t==0) { float ss = sm[0]+sm[1]+sm[2]+sm[3]; stats[blockIdx.x] = make_float2(mx, 1.f/ss); }
}

// P[b][e][d] = exp(ES-mx)*inv * (Ah+Al)
__global__ __launch_bounds__(256)
void pmul_kernel(const float* __restrict__ ES, const ushort* __restrict__ AGGcat,
                 const float2* __restrict__ stats, ushort* __restrict__ P)
{
  const int b = blockIdx.x >> 6, e0 = (blockIdx.x & 63) * 32;
  const int t = threadIdx.x, tx = t & 63, ty = t >> 6;
  const int d4 = tx*4;
  const float2 st0 = stats[b*256+d4+0], st1 = stats[b*256+d4+1];
  const float2 st2 = stats[b*256+d4+2], st3 = stats[b*256+d4+3];
  for (int e = e0+ty; e < e0+32; e += 4) {
    const size_t ro = (size_t)b*2048 + e;
    float4 es = *(const float4*)(ES + ro*256 + d4);
    ushort4 ah = *(const ushort4*)(AGGcat + ro*512 + d4);
    ushort4 al = *(const ushort4*)(AGGcat + ro*512 + 256 + d4);
    ushort4 o;
    o.x = f2bf(__expf(es.x-st0.x)*st0.y*(bf2f(ah.x)+bf2f(al.x)));
    o.y = f2bf(__expf(es.y-st1.x)*st1.y*(bf2f(ah.y)+bf2f(al.y)));
    o.z = f2bf(__expf(es.z-st2.x)*st2.y*(bf2f(ah.z)+bf2f(al.z)));
    o.w = f2bf(__expf(es.w-st3.x)*st3.y*(bf2f(ah.w)+bf2f(al.w)));
    *(ushort4*)(P + ro*256 + d4) = o;
  }
}

__global__ __launch_bounds__(256)
void inc_copy_kernel(const float4* __restrict__ src, float4* __restrict__ dst, size_t n4)
{
  size_t i = (size_t)blockIdx.x*256 + threadIdx.x;
  const size_t stride = (size_t)gridDim.x*256;
  for (; i < n4; i += stride) dst[i] = src[i];
}

// ===================== host =====================
extern "C" void kernel_launch(void* const* d_in, const int* in_sizes, int n_in,
                              void* d_out, int out_size, void* d_ws, size_t ws_size,
                              hipStream_t stream) {
  const float* feat    = (const float*)d_in[0];
  const float* inc     = (const float*)d_in[1];
  const float* vcWatt  = (const float*)d_in[2];
  const float* vcWproj = (const float*)d_in[3];
  // d_in[4] vc_alpha: unused (edge_feats == ef_base every layer); d_in[5] ec_W_att: dead code
  const float* ecWproj = (const float*)d_in[6];
  const float* ecAlpha = (const float*)d_in[7];
  const int*   nLayers = (const int*)d_in[8];

  const int Bb=4, Mm=4096, E=2048, D=256;
  const size_t nodeN = (size_t)Bb*Mm*D, edgeN = (size_t)Bb*E*D, incN = (size_t)Bb*Mm*E;

  const int kparts = 8;
  const size_t fTB    = (size_t)Bb*256*8192*2;   // 16.78 MB
  const size_t partsB = (size_t)kparts*Bb*E*D*4; // 67.1 MB
  const size_t AGGcatB= (size_t)Bb*E*512*2;      // 8.39 MB
  const size_t ESB    = (size_t)Bb*E*D*4;        // 8.39 MB
  const size_t EStB   = ESB;                     // 8.39 MB
  const size_t PB     = edgeN*2;                 // 4.19 MB
  const size_t edgeTB = edgeN*2;                 // 4.19 MB
  const size_t WtB    = nodeN*2;                 // 8.39 MB
  const size_t WsB    = (size_t)3*256*512*2;
  const size_t statB  = (size_t)Bb*256*sizeof(float2);
  const size_t incTB  = incN*2, incbfB = incN*2; // 67.1 MB each
  const size_t needB  = fTB+partsB+AGGcatB+ESB+EStB+PB+edgeTB+WtB+WsB+statB;
  const bool planA = ws_size >= needB + incTB + incbfB;

  char* ws = (char*)d_ws;
  ushort* fT    = (ushort*)ws;  ws += fTB;
  float*  parts = (float*)ws;   ws += partsB;
  ushort* AGGcat= (ushort*)ws;  ws += AGGcatB;
  float*  ES    = (float*)ws;   ws += ESB;
  float*  ESt   = (float*)ws;   ws += EStB;
  ushort* P     = (ushort*)ws;  ws += PB;
  ushort* edgeT = (ushort*)ws;  ws += edgeTB;
  ushort* Wt    = (ushort*)ws;  ws += WtB;
  ushort* Ws0   = (ushort*)ws;            // vc_W_att
  ushort* Ws1   = Ws0 + 256*512;          // vc_W_proj
  ushort* Ws2   = Ws1 + 256*512;          // ec_W_proj
  ws += WsB;
  float2* stats = (float2*)ws;  ws += statB;

  float* outNode = (float*)d_out;
  float* outEdge = outNode + nodeN;
  float* outInc  = outEdge + edgeN;
  ushort* incT, *incbf;
  if (planA) { incT = (ushort*)ws; incbf = incT + incN; }
  else       { incT = (ushort*)outInc; incbf = incT + incN; }  // scratch in outInc, fixed by copy

  const long long kpC = (long long)Bb*E*D;  // part stride (floats)
  dim3 blk(256);

  // 0. weight splits + input transposes
  cvt_w_kernel<<<dim3(64), blk, 0, stream>>>((const float4*)vcWatt,  Ws0);
  cvt_w_kernel<<<dim3(64), blk, 0, stream>>>((const float4*)vcWproj, Ws1);
  cvt_w_kernel<<<dim3(64), blk, 0, stream>>>((const float4*)ecWproj, Ws2);
  trans_feat_kernel<<<dim3(64,4,4), blk, 0, stream>>>(feat, fT);
  trans_inc_kernel<<<dim3(64,32,4), blk, 0, stream>>>(inc, outInc, planA ? 1 : 0, incbf, incT);

  // 1. AGG parts = incT @ fT^T   (K=8192: fh then fl, inc wraps; split-K)
  gemm_kernel<1,0,0,4><<<dim3(16,2,4*kparts), blk, 0, stream>>>(
      incT, 4096, (long long)E*4096, fT, 8192, (long long)256*8192,
      parts, nullptr, D, (long long)E*D, 0, 0, kpC, 8192/kparts, kparts,
      nullptr, nullptr, nullptr);

  // 2. sum parts -> AGGcat [e][512] = [Ah|Al]
  aggsum_kernel<<<dim3(2048), blk, 0, stream>>>(parts, kpC, kparts, AGGcat);

  // 3. ES = AGG @ vcWatt^T  (4-term hi/lo, K=1024) -> f32 [e][256] + transposed [256][2048]
  gemm_kernel<5,3,6,2><<<dim3(32,4,4), blk, 0, stream>>>(
      AGGcat, 512, (long long)E*512, Ws0, 512, 0,
      ES, ESt, D, (long long)E*D, E, (long long)D*E, 0, 1024, 1,
      nullptr, nullptr, nullptr);

  // 4. softmax stats + P
  stats_kernel<<<dim3(Bb*256), blk, 0, stream>>>(ESt, stats);
  pmul_kernel<<<dim3(Bb*64), blk, 0, stream>>>(ES, AGGcat, stats, P);

  // 5. edge_out = P @ vcWproj^T (K=512 hi/lo) -> f32 out + bf16 transposed edgeT
  gemm_kernel<4,3,7,2><<<dim3(32,4,4), blk, 0, stream>>>(
      P, 256, (long long)E*D, Ws1, 512, 0,
      outEdge, edgeT, D, (long long)E*D, E, (long long)D*E, 0, 512, 1,
      nullptr, nullptr, nullptr);

  // 6. Wt = inc @ edge_out  (K=2048) -> bf16
  gemm_kernel<0,0,1,2><<<dim3(64,4,4), blk, 0, stream>>>(
      incbf, 2048, (long long)Mm*E, edgeT, 2048, (long long)D*E,
      Wt, nullptr, D, (long long)Mm*D, 0, 0, 0, 2048, 1,
      nullptr, nullptr, nullptr);

  // 7. node_out = a^L*feat + (1-a^L)*(Wt @ ecWproj^T)  (K=512 dup/hi-lo)
  gemm_kernel<4,3,2,2><<<dim3(64,4,4), blk, 0, stream>>>(
      Wt, 256, (long long)Mm*D, Ws2, 512, 0,
      outNode, nullptr, D, (long long)Mm*D, 0, 0, 0, 512, 1,
      feat, ecAlpha, nLayers);

  // 8. plan B: restore inc passthrough (overwrites incT/incbf scratch)
  if (!planA)
    inc_copy_kernel<<<dim3(2048), blk, 0, stream>>>((const float4*)inc, (float4*)outInc, incN/4);
}